// Round 1
// baseline (419.957 us; speedup 1.0000x reference)
//
#include <hip/hip_runtime.h>

#define EPS_K 1e-7f

typedef __attribute__((ext_vector_type(8))) short  frag8;   // 8 bf16 (4 VGPRs)
typedef __attribute__((ext_vector_type(16))) float accf16;  // MFMA C/D

__device__ __forceinline__ unsigned short f2bf(float f) {
  union { float f; unsigned u; } v; v.f = f;
  unsigned u = v.u;
  u += 0x7FFFu + ((u >> 16) & 1u);   // round-to-nearest-even
  return (unsigned short)(u >> 16);
}

__device__ __forceinline__ float bf2f(unsigned short s) {
  union { unsigned u; float f; } v; v.u = ((unsigned)s) << 16;
  return v.f;
}

// Shapes: inputs/mask (512,32,2048), W (2048,32,32), b (2048,32), out (512,32)
// Per s: Z^T = A*B with A[m=u][k=t] = W[s][t][u], B[k=t][n=b] = x[b][t]
// C layout (32x32): col = lane&31 = b, row = (r&3)+8*(r>>2)+4*(lane>>5) = u
__global__ __launch_bounds__(256, 2) void attn_fused(
    const float* __restrict__ inp,
    const float* __restrict__ msk,
    const float* __restrict__ Wt,
    const float* __restrict__ bias,
    float* __restrict__ out)
{
  // 64 KB exactly: bf16 x-tile, layout us-index = b*1024 + t*32 + (s ^ 2*(b&15))
  __shared__ unsigned short x_us[32 * 1024];

  const int tid = threadIdx.x;
  const int st  = blockIdx.x >> 4;   // s-tile 0..63
  const int bg  = blockIdx.x & 15;   // b-group 0..15
  const int s0  = st * 32;

  // ---- stage x = inp*msk tile into LDS (coalesced float4 over s) ----
  {
    const int c = tid & 7;           // s-chunk of 4 floats
    const int t = tid >> 3;          // 0..31
    unsigned* x32 = (unsigned*)x_us;
    #pragma unroll 4
    for (int b = 0; b < 32; ++b) {
      const int gidx = ((bg * 32 + b) * 32 + t) * 2048 + s0 + 4 * c;
      const float4 vi = *(const float4*)(inp + gidx);
      const float4 vm = *(const float4*)(msk + gidx);
      const int k2 = 2 * (b & 15);
      const unsigned p0 = (unsigned)f2bf(vi.x * vm.x) | ((unsigned)f2bf(vi.y * vm.y) << 16);
      const unsigned p1 = (unsigned)f2bf(vi.z * vm.z) | ((unsigned)f2bf(vi.w * vm.w) << 16);
      const int base = b * 1024 + t * 32;
      // XOR by even k2 keeps ushort pairs dword-adjacent -> two b32 writes
      x32[(base + ((4 * c)     ^ k2)) >> 1] = p0;
      x32[(base + ((4 * c + 2) ^ k2)) >> 1] = p1;
    }
  }
  __syncthreads();

  const int lane = tid & 63;
  const int wv   = tid >> 6;         // wave 0..3 -> s_local = wv*8 + si
  const int n    = lane & 31;        // batch col (B-frag n, C col)
  const int h    = lane >> 5;        // half-wave -> k-block / row group
  const int k2n  = 2 * (n & 15);

  float O[16];
  #pragma unroll
  for (int r = 0; r < 16; ++r) O[r] = 0.f;

  for (int si = 0; si < 8; ++si) {
    const int sl = wv * 8 + si;
    const int s  = s0 + sl;
    const float* Wp = Wt + s * 1024;

    // A-frag: A[m=n][k=8h+j] = W[s][8h+j][n]; coalesced across n-lanes.
    // B-frag: B[k=8h+j][n]   = x[b=n][t=8h+j][sl] from LDS (<=2-way banks).
    frag8 a1, a2, b1, b2;
    #pragma unroll
    for (int j = 0; j < 8; ++j) {
      const int t1 = 8 * h + j;
      a1[j] = (short)f2bf(Wp[t1 * 32 + n]);
      a2[j] = (short)f2bf(Wp[(t1 + 16) * 32 + n]);
      b1[j] = (short)x_us[n * 1024 + t1 * 32 + (sl ^ k2n)];
      b2[j] = (short)x_us[n * 1024 + (t1 + 16) * 32 + (sl ^ k2n)];
    }

    // bias folded into accumulator init: z = x.W[s] + b[s]
    accf16 acc;
    #pragma unroll
    for (int r = 0; r < 16; ++r) {
      const int u = (r & 3) + 8 * (r >> 2) + 4 * h;
      acc[r] = bias[s * 32 + u];
    }
    acc = __builtin_amdgcn_mfma_f32_32x32x16_bf16(a1, b1, acc, 0, 0, 0);
    acc = __builtin_amdgcn_mfma_f32_32x32x16_bf16(a2, b2, acc, 0, 0, 0);

    // e = exp(tanh(z)); tanh(z) = 1 - 2/(exp(2z)+1)  (inf-safe at both ends)
    float e[16];
    float ps = 0.f;
    #pragma unroll
    for (int r = 0; r < 16; ++r) {
      const float z  = acc[r];
      const float e2 = __expf(2.f * z);
      const float th = 1.f - 2.f / (e2 + 1.f);
      e[r] = __expf(th);
      ps  += e[r];
    }
    // row sum over u: 16 in-lane + partner lane (lane ^ 32)
    const float tot = ps + __shfl_xor(ps, 32, 64);
    const float inv = 1.f / (tot + EPS_K);

    #pragma unroll
    for (int r = 0; r < 16; ++r) {
      const int u = (r & 3) + 8 * (r >> 2) + 4 * h;
      O[r] += e[r] * inv * bf2f(x_us[n * 1024 + u * 32 + (sl ^ k2n)]);
    }
  }

  // out[b][u] partial for this block's s-tile: one atomic per (b,u) per wave
  float* op = out + (bg * 32 + n) * 32;
  #pragma unroll
  for (int r = 0; r < 16; ++r) {
    const int u = (r & 3) + 8 * (r >> 2) + 4 * h;
    atomicAdd(op + u, O[r]);
  }
}

extern "C" void kernel_launch(void* const* d_in, const int* in_sizes, int n_in,
                              void* d_out, int out_size, void* d_ws, size_t ws_size,
                              hipStream_t stream) {
  const float* inp  = (const float*)d_in[0];   // (512,32,2048) f32
  const float* msk  = (const float*)d_in[1];   // (512,32,2048) f32
  const float* Wt   = (const float*)d_in[2];   // (2048,32,32)  f32
  const float* bias = (const float*)d_in[3];   // (2048,32)     f32
  float* out = (float*)d_out;                  // (512,32)      f32

  hipMemsetAsync(out, 0, (size_t)out_size * sizeof(float), stream);
  attn_fused<<<dim3(64 * 16), dim3(256), 0, stream>>>(inp, msk, Wt, bias, out);
}

// Round 2
// 325.099 us; speedup vs baseline: 1.2918x; 1.2918x over previous
//
#include <hip/hip_runtime.h>

#define EPS_K 1e-7f

typedef __attribute__((ext_vector_type(8))) short  frag8;   // 8 bf16 (4 VGPRs)
typedef __attribute__((ext_vector_type(16))) float accf16;  // MFMA C/D

__device__ __forceinline__ unsigned f2bf(float f) {
  union { float f; unsigned u; } v; v.f = f;
  unsigned u = v.u;
  u += 0x7FFFu + ((u >> 16) & 1u);   // round-to-nearest-even
  return u >> 16;
}

__device__ __forceinline__ float bf2f(unsigned short s) {
  union { unsigned u; float f; } v; v.u = ((unsigned)s) << 16;
  return v.f;
}

// x-tile LDS index (u16 units): b in [0,32), t in [0,32), s in [0,16)
// swizzles: t' = t ^ ((b>>3)&3), s' = s ^ (2*(b&7))  -> compute reads hit all
// 32 banks across the 32 b-lanes (conflict-free).
__device__ __forceinline__ int xidx(int b, int t, int s) {
  const int tp = t ^ ((b >> 3) & 3);
  const int sp = s ^ (2 * (b & 7));
  return b * 512 + tp * 16 + sp;
}

// Shapes: inputs/mask (512,32,2048), W (2048,32,32), b (2048,32), out (512,32)
// Per s: Z^T = A*B, A[m=u][k=t]=W[s][t][u], B[k=t][n=b]=x[b][t]
// C layout (32x32): col = lane&31 = b, row = (r&3)+8*(r>>2)+4*(lane>>5) = u
template <bool USE_WS>
__global__ __launch_bounds__(256, 4) void attn_fused(
    const float* __restrict__ inp,
    const float* __restrict__ msk,
    const float* __restrict__ Wt,
    const float* __restrict__ bias,
    float* __restrict__ part,
    float* __restrict__ out)
{
  // 32 KB bf16 x-tile (32 b x 32 t x 16 s); reused as float red[4096] later
  __shared__ unsigned short x_us[32 * 512];

  const int tid = threadIdx.x;
  const int st  = blockIdx.x >> 4;   // s-tile 0..127
  const int bg  = blockIdx.x & 15;   // b-group 0..15
  const int s0  = st * 16;

  // ---- stage x = inp*msk tile into LDS (float4 over s) ----
  {
    const int c  = tid & 3;          // s-chunk of 4 floats
    const int t  = (tid >> 2) & 31;
    const int bh = tid >> 7;         // b-half
    unsigned* x32 = (unsigned*)x_us;
    #pragma unroll 4
    for (int bs = 0; bs < 16; ++bs) {
      const int b = bh * 16 + bs;
      const int gidx = ((bg * 32 + b) * 32 + t) * 2048 + s0 + 4 * c;
      const float4 vi = *(const float4*)(inp + gidx);
      const float4 vm = *(const float4*)(msk + gidx);
      const int tp = t ^ ((b >> 3) & 3);
      const int k  = b & 7;
      const unsigned p0 = f2bf(vi.x * vm.x) | (f2bf(vi.y * vm.y) << 16);
      const unsigned p1 = f2bf(vi.z * vm.z) | (f2bf(vi.w * vm.w) << 16);
      const int base = b * 256 + tp * 8;   // dword units
      x32[base + ((2 * c)     ^ k)] = p0;
      x32[base + ((2 * c + 1) ^ k)] = p1;
    }
  }
  __syncthreads();

  const int lane = tid & 63;
  const int wv   = tid >> 6;         // wave 0..3 -> s_local = wv*4 + si
  const int n    = lane & 31;        // batch col (B-frag n, C col)
  const int h    = lane >> 5;        // half-wave -> k-block / row group

  float O[16];
  #pragma unroll
  for (int r = 0; r < 16; ++r) O[r] = 0.f;

  #pragma unroll
  for (int si = 0; si < 4; ++si) {
    const int sl = wv * 4 + si;
    const int s  = s0 + sl;
    const float* Wp = Wt + s * 1024;

    // A-frag from global (L2-hot, coalesced over n); B-frag from LDS.
    frag8 a1, a2, b1, b2;
    #pragma unroll
    for (int j = 0; j < 8; ++j) {
      const int t1 = 8 * h + j;
      a1[j] = (short)f2bf(Wp[t1 * 32 + n]);
      a2[j] = (short)f2bf(Wp[(t1 + 16) * 32 + n]);
      b1[j] = (short)x_us[xidx(n, t1, sl)];
      b2[j] = (short)x_us[xidx(n, t1 + 16, sl)];
    }

    // bias folded into accumulator init: z = x.W[s] + b[s]
    accf16 acc;
    #pragma unroll
    for (int r = 0; r < 16; ++r) {
      const int u = (r & 3) + 8 * (r >> 2) + 4 * h;
      acc[r] = bias[s * 32 + u];
    }
    acc = __builtin_amdgcn_mfma_f32_32x32x16_bf16(a1, b1, acc, 0, 0, 0);
    acc = __builtin_amdgcn_mfma_f32_32x32x16_bf16(a2, b2, acc, 0, 0, 0);

    // e = exp(tanh(z)); tanh(z) = 1 - 2/(exp(2z)+1)
    float e[16];
    float ps = 0.f;
    #pragma unroll
    for (int r = 0; r < 16; ++r) {
      const float z  = acc[r];
      const float e2 = __expf(2.f * z);
      const float th = 1.f - 2.f / (e2 + 1.f);
      e[r] = __expf(th);
      ps  += e[r];
    }
    const float tot = ps + __shfl_xor(ps, 32, 64);
    const float inv = 1.f / (tot + EPS_K);

    #pragma unroll
    for (int r = 0; r < 16; ++r) {
      const int u = (r & 3) + 8 * (r >> 2) + 4 * h;
      O[r] += e[r] * inv * bf2f(x_us[xidx(n, u, sl)]);
    }
  }

  // ---- cross-wave reduction in LDS (no atomics) ----
  __syncthreads();                   // everyone done reading x_us
  float* red = (float*)x_us;
  #pragma unroll
  for (int r = 0; r < 16; ++r) {
    const int u = (r & 3) + 8 * (r >> 2) + 4 * h;
    red[wv * 1024 + n * 32 + (u ^ n)] = O[r];  // ^n: conflict-free banks
  }
  __syncthreads();

  // 256 threads x 4 consecutive outputs each -> float4 store
  const int q0 = tid * 4;
  float4 v;
  float* vp = (float*)&v;
  #pragma unroll
  for (int i = 0; i < 4; ++i) {
    const int q = q0 + i;
    const int b = q >> 5, u = q & 31;
    float sum = 0.f;
    #pragma unroll
    for (int w = 0; w < 4; ++w) sum += red[w * 1024 + b * 32 + (u ^ b)];
    vp[i] = sum;
  }
  if (USE_WS) {
    *(float4*)(part + (size_t)st * 16384 + bg * 1024 + q0) = v;
  } else {
    float* op = out + bg * 1024 + q0;
    #pragma unroll
    for (int i = 0; i < 4; ++i) atomicAdd(op + i, vp[i]);
  }
}

// out[f] = sum over 128 s-tiles of part[st][f]; fully coalesced.
__global__ __launch_bounds__(256) void reduce_part(
    const float* __restrict__ part, float* __restrict__ out)
{
  const int f = blockIdx.x * 256 + threadIdx.x;   // 64 blocks x 256
  float s = 0.f;
  #pragma unroll 8
  for (int st = 0; st < 128; ++st) s += part[(size_t)st * 16384 + f];
  out[f] = s;
}

extern "C" void kernel_launch(void* const* d_in, const int* in_sizes, int n_in,
                              void* d_out, int out_size, void* d_ws, size_t ws_size,
                              hipStream_t stream) {
  const float* inp  = (const float*)d_in[0];   // (512,32,2048) f32
  const float* msk  = (const float*)d_in[1];   // (512,32,2048) f32
  const float* Wt   = (const float*)d_in[2];   // (2048,32,32)  f32
  const float* bias = (const float*)d_in[3];   // (2048,32)     f32
  float* out = (float*)d_out;                  // (512,32)      f32

  const size_t need = (size_t)128 * 16384 * sizeof(float);  // 8 MB partials
  if (ws_size >= need) {
    attn_fused<true><<<dim3(128 * 16), dim3(256), 0, stream>>>(
        inp, msk, Wt, bias, (float*)d_ws, out);
    reduce_part<<<dim3(64), dim3(256), 0, stream>>>((const float*)d_ws, out);
  } else {
    hipMemsetAsync(out, 0, (size_t)out_size * sizeof(float), stream);
    attn_fused<false><<<dim3(128 * 16), dim3(256), 0, stream>>>(
        inp, msk, Wt, bias, nullptr, out);
  }
}

// Round 4
// 311.282 us; speedup vs baseline: 1.3491x; 1.0444x over previous
//
#include <hip/hip_runtime.h>

#define EPS_K 1e-7f

typedef __attribute__((ext_vector_type(8)))  short          frag8;  // 8 bf16 (4 VGPRs)
typedef __attribute__((ext_vector_type(16))) float          accf16; // MFMA C/D
typedef __attribute__((ext_vector_type(4)))  unsigned short us4;    // 8B LDS read

__device__ __forceinline__ unsigned f2bf(float f) {
  union { float f; unsigned u; } v; v.f = f;
  unsigned u = v.u;
  u += 0x7FFFu + ((u >> 16) & 1u);   // RNE
  return u >> 16;
}
__device__ __forceinline__ float bf2f(unsigned short s) {
  union { unsigned u; float f; } v; v.u = ((unsigned)s) << 16;
  return v.f;
}
__device__ __forceinline__ unsigned pk_bf16(float lo, float hi) {
  return f2bf(lo) | (f2bf(hi) << 16);
}

// ---------------------------------------------------------------------------
// Pre-pass: W (2048,32,32) f32 [s][t][u]  ->  Wbf bf16 [s][u][t] (4 MB in ws)
// ---------------------------------------------------------------------------
__global__ __launch_bounds__(256) void wbf_prep(
    const float* __restrict__ Wt, unsigned short* __restrict__ Wbf)
{
  __shared__ unsigned short tile[32 * 33];     // [t][u], pad 33
  const int s   = blockIdx.x;
  const int tid = threadIdx.x;
  {
    const int t  = tid >> 3;
    const int uc = tid & 7;                    // u-chunk of 4
    const float4 v = *(const float4*)(Wt + s * 1024 + t * 32 + 4 * uc);
    tile[t * 33 + 4 * uc + 0] = (unsigned short)f2bf(v.x);
    tile[t * 33 + 4 * uc + 1] = (unsigned short)f2bf(v.y);
    tile[t * 33 + 4 * uc + 2] = (unsigned short)f2bf(v.z);
    tile[t * 33 + 4 * uc + 3] = (unsigned short)f2bf(v.w);
  }
  __syncthreads();
  {
    const int u  = tid >> 3;
    const int tc = tid & 7;                    // t-chunk of 4
    uint2 d;
    d.x = (unsigned)tile[(4 * tc + 0) * 33 + u] | ((unsigned)tile[(4 * tc + 1) * 33 + u] << 16);
    d.y = (unsigned)tile[(4 * tc + 2) * 33 + u] | ((unsigned)tile[(4 * tc + 3) * 33 + u] << 16);
    *(uint2*)(Wbf + s * 1024 + u * 32 + 4 * tc) = d;  // lanes tc -> 64B contig
  }
}

// ---------------------------------------------------------------------------
// Main kernel. Shapes: inputs/mask (512,32,2048), W (2048,32,32), b (2048,32),
// out (512,32). Per s: Z^T = A*B, A[m=u][k=t]=W[s][t][u], B[k=t][n=b]=x[b][t].
// C layout (32x32, m74/m101 + HW-validated R1/R2):
//   col = lane&31 = b, row = (r&3)+8*(r>>2)+4*(lane>>5) = u
//
// x-tile LDS (bf16): per-b region of 64 16B-chunks; chunk L = (t>>3)*16 + s,
// swizzled L' = L ^ (b&7); element within chunk = t&7.
//   -> B-frag = ds_read_b128, O-update = ds_read_b64, staging = ds_write_b128,
//      all with stride-1-equivalent bank distribution (free).
// ---------------------------------------------------------------------------
template <bool WBF, bool USE_WS>
__global__ __launch_bounds__(256, 5) void attn_fused(
    const float* __restrict__ inp,
    const float* __restrict__ msk,
    const float* __restrict__ Wt,
    const unsigned short* __restrict__ Wbf,
    const float* __restrict__ bias,
    float* __restrict__ part,
    float* __restrict__ out)
{
  __shared__ unsigned short x_us[32 * 512];    // 32 KB

  const int tid = threadIdx.x;
  const int st  = blockIdx.x >> 4;             // s-tile 0..127
  const int bg  = blockIdx.x & 15;             // b-group 0..15
  const int s0  = st * 16;

  // ---- stage x = inp*msk (thread owns b, 8 t, 4 s -> whole 16B chunks) ----
  #pragma unroll
  for (int iter = 0; iter < 2; ++iter) {
    const int idx = iter * 256 + tid;
    const int sc  = idx & 3;                   // s-quad
    const int tb  = (idx >> 2) & 3;            // t-block of 8
    const int b   = idx >> 4;                  // 0..31
    const float* ip = inp + ((size_t)(bg * 32 + b) * 32 + 8 * tb) * 2048 + s0 + 4 * sc;
    const float* mp = msk + ((size_t)(bg * 32 + b) * 32 + 8 * tb) * 2048 + s0 + 4 * sc;
    unsigned c32[4][4];                        // [w][dword j2]
    #pragma unroll
    for (int j2 = 0; j2 < 4; ++j2) {
      const float4 vi0 = *(const float4*)(ip + (2 * j2)     * 2048);
      const float4 vm0 = *(const float4*)(mp + (2 * j2)     * 2048);
      const float4 vi1 = *(const float4*)(ip + (2 * j2 + 1) * 2048);
      const float4 vm1 = *(const float4*)(mp + (2 * j2 + 1) * 2048);
      c32[0][j2] = pk_bf16(vi0.x * vm0.x, vi1.x * vm1.x);
      c32[1][j2] = pk_bf16(vi0.y * vm0.y, vi1.y * vm1.y);
      c32[2][j2] = pk_bf16(vi0.z * vm0.z, vi1.z * vm1.z);
      c32[3][j2] = pk_bf16(vi0.w * vm0.w, vi1.w * vm1.w);
    }
    #pragma unroll
    for (int w = 0; w < 4; ++w) {
      const int L = tb * 16 + 4 * sc + w;
      unsigned* dst = (unsigned*)(x_us + b * 512 + ((L ^ (b & 7)) * 8));
      *(uint4*)dst = make_uint4(c32[w][0], c32[w][1], c32[w][2], c32[w][3]);
    }
  }
  __syncthreads();

  const int lane = tid & 63;
  const int wv   = tid >> 6;                   // wave 0..3 -> s_local = wv*4+si
  const int n    = lane & 31;                  // b (B-frag n, C col) / u (A-frag m)
  const int h    = lane >> 5;                  // half-wave -> k-block / row group
  const int nx   = n & 7;

  float O[16];
  #pragma unroll
  for (int r = 0; r < 16; ++r) O[r] = 0.f;

  #pragma unroll
  for (int si = 0; si < 4; ++si) {
    const int sl = wv * 4 + si;
    const int s  = s0 + sl;

    // A-frag
    frag8 a1, a2;
    if (WBF) {
      const unsigned short* wp = Wbf + s * 1024 + n * 32 + 8 * h;
      a1 = *(const frag8*)(wp);
      a2 = *(const frag8*)(wp + 16);
    } else {
      const float* Wp = Wt + s * 1024;
      #pragma unroll
      for (int j = 0; j < 8; ++j) {
        const int t1 = 8 * h + j;
        a1[j] = (short)f2bf(Wp[t1 * 32 + n]);
        a2[j] = (short)f2bf(Wp[(t1 + 16) * 32 + n]);
      }
    }

    // B-frag: chunks L = h*16+sl (t=8h..8h+7) and (h+2)*16+sl (t=+16)
    const frag8 b1 = *(const frag8*)(x_us + n * 512 + (((h      * 16 + sl) ^ nx) * 8));
    const frag8 b2 = *(const frag8*)(x_us + n * 512 + ((((h + 2) * 16 + sl) ^ nx) * 8));

    // bias -> accumulator init (4 broadcast dwordx4)
    accf16 acc;
    #pragma unroll
    for (int g = 0; g < 4; ++g) {
      const float4 bb = *(const float4*)(bias + s * 32 + 8 * g + 4 * h);
      acc[4 * g + 0] = bb.x; acc[4 * g + 1] = bb.y;
      acc[4 * g + 2] = bb.z; acc[4 * g + 3] = bb.w;
    }
    acc = __builtin_amdgcn_mfma_f32_32x32x16_bf16(a1, b1, acc, 0, 0, 0);
    acc = __builtin_amdgcn_mfma_f32_32x32x16_bf16(a2, b2, acc, 0, 0, 0);

    // e = exp(tanh(z)); tanh(z) = 1 - 2/(exp(2z)+1)
    float e[16];
    float ps = 0.f;
    #pragma unroll
    for (int r = 0; r < 16; ++r) {
      const float z  = acc[r];
      const float e2 = __expf(2.f * z);
      const float th = 1.f - 2.f / (e2 + 1.f);
      e[r] = __expf(th);
      ps  += e[r];
    }
    const float tot = ps + __shfl_xor(ps, 32, 64);
    const float inv = 1.f / (tot + EPS_K);

    // O += att * x ; x re-read as 4 x ds_read_b64 (u = 8g+4h+i -> r = 4g+i)
    #pragma unroll
    for (int g = 0; g < 4; ++g) {
      const us4 xv = *(const us4*)(x_us + n * 512 + (((g * 16 + sl) ^ nx) * 8) + 4 * h);
      #pragma unroll
      for (int i = 0; i < 4; ++i)
        O[4 * g + i] += e[4 * g + i] * inv * bf2f(xv[i]);
    }
  }

  // ---- cross-wave reduction in LDS (no atomics) ----
  __syncthreads();
  float* red = (float*)x_us;
  #pragma unroll
  for (int r = 0; r < 16; ++r) {
    const int u = (r & 3) + 8 * (r >> 2) + 4 * h;
    red[wv * 1024 + n * 32 + (u ^ n)] = O[r];
  }
  __syncthreads();

  const int q0 = tid * 4;
  float4 v;
  float* vp = (float*)&v;
  #pragma unroll
  for (int i = 0; i < 4; ++i) {
    const int q = q0 + i;
    const int b = q >> 5, u = q & 31;
    float sum = 0.f;
    #pragma unroll
    for (int w = 0; w < 4; ++w) sum += red[w * 1024 + b * 32 + (u ^ b)];
    vp[i] = sum;
  }
  if (USE_WS) {
    *(float4*)(part + (size_t)st * 16384 + bg * 1024 + q0) = v;
  } else {
    float* op = out + bg * 1024 + q0;
    #pragma unroll
    for (int i = 0; i < 4; ++i) atomicAdd(op + i, vp[i]);
  }
}

// out[f] = sum over 128 s-tiles of part[st][f]
__global__ __launch_bounds__(256) void reduce_part(
    const float* __restrict__ part, float* __restrict__ out)
{
  const int f = blockIdx.x * 256 + threadIdx.x;
  float s = 0.f;
  #pragma unroll 8
  for (int st = 0; st < 128; ++st) s += part[(size_t)st * 16384 + f];
  out[f] = s;
}

extern "C" void kernel_launch(void* const* d_in, const int* in_sizes, int n_in,
                              void* d_out, int out_size, void* d_ws, size_t ws_size,
                              hipStream_t stream) {
  const float* inp  = (const float*)d_in[0];   // (512,32,2048) f32
  const float* msk  = (const float*)d_in[1];   // (512,32,2048) f32
  const float* Wt   = (const float*)d_in[2];   // (2048,32,32)  f32
  const float* bias = (const float*)d_in[3];   // (2048,32)     f32
  float* out = (float*)d_out;                  // (512,32)      f32

  const size_t part_sz = (size_t)128 * 16384 * sizeof(float);          // 8 MB
  const size_t wbf_sz  = (size_t)2048 * 1024 * sizeof(unsigned short); // 4 MB

  if (ws_size >= part_sz + wbf_sz) {
    float* part = (float*)d_ws;
    unsigned short* Wbf = (unsigned short*)((char*)d_ws + part_sz);
    wbf_prep<<<dim3(2048), dim3(256), 0, stream>>>(Wt, Wbf);
    attn_fused<true, true><<<dim3(2048), dim3(256), 0, stream>>>(
        inp, msk, Wt, Wbf, bias, part, out);
    reduce_part<<<dim3(64), dim3(256), 0, stream>>>(part, out);
  } else if (ws_size >= part_sz) {
    float* part = (float*)d_ws;
    attn_fused<false, true><<<dim3(2048), dim3(256), 0, stream>>>(
        inp, msk, Wt, nullptr, bias, part, out);
    reduce_part<<<dim3(64), dim3(256), 0, stream>>>(part, out);
  } else {
    (void)hipMemsetAsync(out, 0, (size_t)out_size * sizeof(float), stream);
    attn_fused<false, false><<<dim3(2048), dim3(256), 0, stream>>>(
        inp, msk, Wt, nullptr, bias, nullptr, out);
  }
}